// Round 3
// baseline (822.785 us; speedup 1.0000x reference)
//
#include <hip/hip_runtime.h>

#define T_STEPS 512
#define B_ENV   256
#define D_IN    64
#define H_DIM   128
#define G4      512   // 4*H gate rows

typedef _Float16 h2v __attribute__((ext_vector_type(2)));
typedef _Float16 h8v __attribute__((ext_vector_type(8)));
typedef float    f4v __attribute__((ext_vector_type(4)));

__device__ __forceinline__ float dot2(h2v a, h2v b, float c) {
#if __has_builtin(__builtin_amdgcn_fdot2)
    return __builtin_amdgcn_fdot2(a, b, c, false);
#else
    return c + (float)a.x * (float)b.x + (float)a.y * (float)b.y;
#endif
}

__device__ __forceinline__ h2v pack16(float a, float b) {
#if __has_builtin(__builtin_amdgcn_cvt_pkrtz)
    union { __fp16 __attribute__((ext_vector_type(2))) r; h2v h; } u;
    u.r = __builtin_amdgcn_cvt_pkrtz(a, b);
    return u.h;
#else
    h2v p; p.x = (_Float16)a; p.y = (_Float16)b; return p;
#endif
}

__device__ __forceinline__ float fast_rcp(float x) {
#if __has_builtin(__builtin_amdgcn_rcpf)
    return __builtin_amdgcn_rcpf(x);
#else
    return 1.0f / x;
#endif
}
__device__ __forceinline__ float sigm(float x)   { return fast_rcp(1.0f + __expf(-x)); }
__device__ __forceinline__ float tanh_f(float x) { float e = __expf(2.0f * x); return 1.0f - 2.0f * fast_rcp(e + 1.0f); }

// One block per environment. 896 threads = 14 waves, roles wave-aligned:
//   tid [0,512)   : gate-row threads. w[64] = W_hh row tid (f16 pairs).
//                   Compute full-row dot vs h (LDS broadcast), add xg (pipelined),
//                   apply own activation, write activated gate to g_lds[tid].
//   tid [512,640) : projection threads. w[64] = W_hid row. out[t-1] = w.h_{t-1}+b.
//   tid [640,896) : xg threads. w = 2 rows of W_ih. Compute xg_{t+1} from global x
//                   into xg_lds[(t+1)&1]  (one step ahead, off critical path).
// Cell state c_t lives in registers of threads 0..127. Two barriers per step,
// zero cross-lane reductions.
__global__ __launch_bounds__(896, 4)
void ppo_lstm_scan(const float* __restrict__ x,      // [T,B,D]
                   const float* __restrict__ done,   // [T,B]
                   const float* __restrict__ h0,     // [B,H]
                   const float* __restrict__ c0,     // [B,H]
                   const float* __restrict__ W_ih,   // [4H,D]
                   const float* __restrict__ b_ih,   // [4H]
                   const float* __restrict__ W_hh,   // [4H,H]
                   const float* __restrict__ b_hh,   // [4H]
                   const float* __restrict__ W_hid,  // [H,H]
                   const float* __restrict__ b_hid,  // [H]
                   float* __restrict__ out)          // [T*B,H]
{
    const int b   = blockIdx.x;
    const int tid = threadIdx.x;

    __shared__ h2v   h_lds[H_DIM / 2];   // h_t as f16 pairs (256 B)
    __shared__ float g_lds[G4];          // activated gates (2 KB)
    __shared__ float xg_lds[2][G4];      // pipelined x-projection (4 KB)

    h2v   w[64];
    float bias_a = 0.0f, bias_b = 0.0f;
    float c_reg  = 0.0f;

    // ---- one-time: weight rows -> registers (f16) ----
    if (tid < G4) {
        const float* wr = W_hh + tid * H_DIM;
        #pragma unroll
        for (int c = 0; c < 64; ++c) w[c] = pack16(wr[2*c], wr[2*c+1]);
    } else if (tid < 640) {
        const int pr = tid - G4;
        const float* wr = W_hid + pr * H_DIM;
        #pragma unroll
        for (int c = 0; c < 64; ++c) w[c] = pack16(wr[2*c], wr[2*c+1]);
        bias_a = b_hid[pr];
    } else {
        const int q = tid - 640;
        const float* wr0 = W_ih + q * D_IN;
        const float* wr1 = W_ih + (q + 256) * D_IN;
        #pragma unroll
        for (int c = 0; c < 32; ++c) w[c]      = pack16(wr0[2*c], wr0[2*c+1]);
        #pragma unroll
        for (int c = 0; c < 32; ++c) w[32 + c] = pack16(wr1[2*c], wr1[2*c+1]);
        bias_a = b_ih[q]       + b_hh[q];
        bias_b = b_ih[q + 256] + b_hh[q + 256];
    }

    // ---- one-time: stage h0 (f16), c0 (regs), xg_0 ----
    if (tid < 64) {
        const float* hp = h0 + b * H_DIM;
        h_lds[tid] = pack16(hp[2*tid], hp[2*tid+1]);
    }
    if (tid < H_DIM) c_reg = c0[b * H_DIM + tid];
    if (tid >= 640) {
        const int q = tid - 640;
        const float* xp = x + (size_t)b * D_IN;
        float s0 = 0.f, s1 = 0.f;
        #pragma unroll
        for (int c4 = 0; c4 < 16; ++c4) {
            f4v xx = *reinterpret_cast<const f4v*>(xp + 4*c4);
            h2v xa = pack16(xx.x, xx.y);
            h2v xb = pack16(xx.z, xx.w);
            s0 = dot2(w[2*c4], xa, s0);       s0 = dot2(w[2*c4+1], xb, s0);
            s1 = dot2(w[32+2*c4], xa, s1);    s1 = dot2(w[32+2*c4+1], xb, s1);
        }
        xg_lds[0][q]       = s0 + bias_a;
        xg_lds[0][q + 256] = s1 + bias_b;
    }
    __syncthreads();

    // full-row dot of w[0..63] against h_lds, via b128 broadcast reads
    auto hdot = [&]() -> float {
        const h8v* hp8 = reinterpret_cast<const h8v*>(h_lds);
        float a0 = 0.f, a1 = 0.f, a2 = 0.f, a3 = 0.f;
        #pragma unroll
        for (int c = 0; c < 16; ++c) {
            union { h8v v; h2v p[4]; } u;
            u.v = hp8[c];
            a0 = dot2(w[4*c+0], u.p[0], a0);
            a1 = dot2(w[4*c+1], u.p[1], a1);
            a2 = dot2(w[4*c+2], u.p[2], a2);
            a3 = dot2(w[4*c+3], u.p[3], a3);
        }
        return (a0 + a1) + (a2 + a3);
    };

    for (int t = 0; t < T_STEPS; ++t) {
        const float dmask = 1.0f - done[t * B_ENV + b];

        if (tid < G4) {
            // gates for step t  (h_lds currently holds hs[t-1] / h0)
            float gs = xg_lds[t & 1][tid] + dmask * hdot();
            g_lds[tid] = ((tid >> 7) == 2) ? tanh_f(gs) : sigm(gs);
        } else if (tid < 640) {
            if (t > 0) {
                float po = hdot();  // proj of hs[t-1]
                out[((size_t)(t - 1) * B_ENV + b) * H_DIM + (tid - G4)] = po + bias_a;
            }
        } else if (t + 1 < T_STEPS) {
            // xg for step t+1, off the recurrence critical path
            const int q = tid - 640;
            const float* xp = x + ((size_t)(t + 1) * B_ENV + b) * D_IN;
            float s0 = 0.f, s1 = 0.f;
            #pragma unroll
            for (int c4 = 0; c4 < 16; ++c4) {
                f4v xx = *reinterpret_cast<const f4v*>(xp + 4*c4);
                h2v xa = pack16(xx.x, xx.y);
                h2v xb = pack16(xx.z, xx.w);
                s0 = dot2(w[2*c4], xa, s0);       s0 = dot2(w[2*c4+1], xb, s0);
                s1 = dot2(w[32+2*c4], xa, s1);    s1 = dot2(w[32+2*c4+1], xb, s1);
            }
            const int nb = (t + 1) & 1;
            xg_lds[nb][q]       = s0 + bias_a;
            xg_lds[nb][q + 256] = s1 + bias_b;
        }
        __syncthreads();   // gates ready (and xg_{t+1} ready)

        if (tid < H_DIM) {
            float pi = g_lds[tid];
            float pf = g_lds[H_DIM + tid];
            float pg = g_lds[2 * H_DIM + tid];
            float po = g_lds[3 * H_DIM + tid];
            float cn = pf * (c_reg * dmask) + pi * pg;
            c_reg = cn;
            float hn = po * tanh_f(cn);
            reinterpret_cast<_Float16*>(h_lds)[tid] = (_Float16)hn;
        }
        __syncthreads();   // h_t ready
    }

    // epilogue: out row T-1 from final h
    if (tid >= G4 && tid < 640) {
        float po = hdot();
        out[((size_t)(T_STEPS - 1) * B_ENV + b) * H_DIM + (tid - G4)] = po + bias_a;
    }
}

extern "C" void kernel_launch(void* const* d_in, const int* in_sizes, int n_in,
                              void* d_out, int out_size, void* d_ws, size_t ws_size,
                              hipStream_t stream) {
    const float* x     = (const float*)d_in[0];
    const float* done  = (const float*)d_in[1];
    const float* h0    = (const float*)d_in[2];
    const float* c0    = (const float*)d_in[3];
    const float* W_ih  = (const float*)d_in[4];
    const float* b_ih  = (const float*)d_in[5];
    const float* W_hh  = (const float*)d_in[6];
    const float* b_hh  = (const float*)d_in[7];
    const float* W_hid = (const float*)d_in[8];
    const float* b_hid = (const float*)d_in[9];
    float* out = (float*)d_out;

    hipLaunchKernelGGL(ppo_lstm_scan, dim3(B_ENV), dim3(896), 0, stream,
                       x, done, h0, c0, W_ih, b_ih, W_hh, b_hh, W_hid, b_hid, out);
}